// Round 1
// baseline (83.784 us; speedup 1.0000x reference)
//
#include <hip/hip_runtime.h>
#include <math.h>

#define N 384
#define D 256
#define D4 (D/4)
#define TPB 256
#define MARGIN_F 0.3f

// K1: one block per anchor row i.
//  - computes distance row d[i][:] into LDS (direct ||e_i - e_j||^2, sqrt)
//  - per-row hard-loss stats: hardest_pos, min_neg, row_max, pos_cnt
//  - semi-hard accumulation over (j in positives, k in negatives)
//  - per-block partials -> workspace (no atomics, everything overwritten)
__global__ __launch_bounds__(TPB) void k_rows(const float* __restrict__ e,
                                              const int* __restrict__ labels,
                                              float* __restrict__ semi_sum,
                                              int* __restrict__ semi_cnt,
                                              float* __restrict__ hp_arr,
                                              float* __restrict__ mn_arr,
                                              float* __restrict__ rm_arr,
                                              int* __restrict__ pc_arr) {
  __shared__ float4 ei[D4];      // anchor embedding
  __shared__ float  row[N];      // distances d[i][j]
  __shared__ float  negd[N];     // d if negative else big sentinel
  __shared__ int    lab[N];
  __shared__ int    poslist[N];
  __shared__ int    npos;
  __shared__ float  w_s[4], w_hp[4], w_mn[4], w_rm[4];
  __shared__ int    w_c[4], w_pc[4];

  const int i = blockIdx.x;
  const int t = threadIdx.x;

  if (t < D4) ei[t] = ((const float4*)(e + (size_t)i * D))[t];
  lab[t] = labels[t];
  if (t < N - TPB) lab[t + TPB] = labels[t + TPB];
  if (t == 0) npos = 0;
  __syncthreads();

  const int li = lab[i];

  float l_hp = 0.0f;       // hardest positive (0 if none -> matches (apf*d).max)
  float l_mn = 1e30f;      // min over negatives
  float l_rm = 0.0f;       // row max (for global max_d)
  int   l_pc = 0;          // positive count

  for (int j = t; j < N; j += TPB) {
    const float4* ej = (const float4*)(e + (size_t)j * D);
    float acc = 0.0f;
#pragma unroll 8
    for (int c = 0; c < D4; ++c) {
      float4 a = ei[c];
      float4 b = ej[c];
      float dx = a.x - b.x, dy = a.y - b.y, dz = a.z - b.z, dw = a.w - b.w;
      acc += dx * dx + dy * dy + dz * dz + dw * dw;
    }
    float dv = sqrtf(acc);           // diagonal: acc == 0 exactly -> dv == 0 (ref zmask semantics)
    row[j] = dv;
    bool eq    = (lab[j] == li);
    bool isneg = !eq;
    bool ispos = eq && (j != i);
    negd[j] = isneg ? dv : 1e30f;    // sentinel: loss = ap - 1e30 + m < 0 -> never valid
    l_rm = fmaxf(l_rm, dv);
    if (isneg) l_mn = fminf(l_mn, dv);
    if (ispos) {
      l_hp = fmaxf(l_hp, dv);
      l_pc++;
      int idx = atomicAdd(&npos, 1); // LDS atomic, order irrelevant
      poslist[idx] = j;
    }
  }
  __syncthreads();

  // semi-hard: for each positive j, each thread scans its k's
  float l_sum = 0.0f;
  int   l_cnt = 0;
  const int np = npos;
  for (int p = 0; p < np; ++p) {
    const float ap = row[poslist[p]];
    for (int k = t; k < N; k += TPB) {
      float an   = negd[k];
      float loss = ap - an + MARGIN_F;
      if (an > ap && loss > 0.0f) { l_sum += loss; l_cnt++; }
    }
  }

  // wave(64) shuffle reduction, then cross-wave via LDS
  for (int off = 32; off; off >>= 1) {
    l_sum += __shfl_down(l_sum, off);
    l_cnt += __shfl_down(l_cnt, off);
    l_hp = fmaxf(l_hp, __shfl_down(l_hp, off));
    l_mn = fminf(l_mn, __shfl_down(l_mn, off));
    l_rm = fmaxf(l_rm, __shfl_down(l_rm, off));
    l_pc += __shfl_down(l_pc, off);
  }
  const int wv = t >> 6;
  if ((t & 63) == 0) {
    w_s[wv] = l_sum; w_c[wv] = l_cnt; w_hp[wv] = l_hp;
    w_mn[wv] = l_mn; w_rm[wv] = l_rm; w_pc[wv] = l_pc;
  }
  __syncthreads();
  if (t == 0) {
    float S = 0.0f, HP = 0.0f, MN = 1e30f, RM = 0.0f;
    int C = 0, PC = 0;
    for (int w = 0; w < 4; ++w) {
      S += w_s[w]; C += w_c[w];
      HP = fmaxf(HP, w_hp[w]); MN = fminf(MN, w_mn[w]); RM = fmaxf(RM, w_rm[w]);
      PC += w_pc[w];
    }
    semi_sum[i] = S; semi_cnt[i] = C;
    hp_arr[i] = HP; mn_arr[i] = MN; rm_arr[i] = RM; pc_arr[i] = PC;
  }
}

// K2: single block of 384 threads (one per row) -> final scalar
__global__ __launch_bounds__(N) void k_final(const float* __restrict__ semi_sum,
                                             const int* __restrict__ semi_cnt,
                                             const float* __restrict__ hp_arr,
                                             const float* __restrict__ mn_arr,
                                             const float* __restrict__ rm_arr,
                                             const int* __restrict__ pc_arr,
                                             float* __restrict__ out) {
  const int t = threadIdx.x;        // 0..383, 6 waves
  __shared__ float shf[12];
  __shared__ int   shi[6];
  __shared__ float s_maxd, s_tsum;
  __shared__ int   s_tcnt;

  float s  = semi_sum[t];
  float rm = rm_arr[t];
  int   c  = semi_cnt[t];
  for (int off = 32; off; off >>= 1) {
    s += __shfl_down(s, off);
    rm = fmaxf(rm, __shfl_down(rm, off));
    c += __shfl_down(c, off);
  }
  const int wv = t >> 6;
  if ((t & 63) == 0) { shf[wv] = s; shf[6 + wv] = rm; shi[wv] = c; }
  __syncthreads();
  if (t == 0) {
    float ts = 0.0f, md = 0.0f; int tc = 0;
    for (int w = 0; w < 6; ++w) { ts += shf[w]; md = fmaxf(md, shf[6 + w]); tc += shi[w]; }
    s_tsum = ts; s_tcnt = tc; s_maxd = md;
  }
  __syncthreads();
  const float maxd = s_maxd;

  // hard loss per row:
  //   hardest_neg = min over k of (d + max_d*(1-anf)) = min(min_neg, max_d)
  //   (diagonal d=0 contributes exactly max_d for the non-negative side)
  float hp  = hp_arr[t];
  float mnv = mn_arr[t];
  int   pcv = pc_arr[t];
  float hn  = fminf(mnv, maxd);
  float tl  = fmaxf(hp - hn + MARGIN_F, 0.0f);
  int   vld = (pcv > 0) ? 1 : 0;
  float contrib = vld ? tl : 0.0f;
  for (int off = 32; off; off >>= 1) {
    contrib += __shfl_down(contrib, off);
    vld += __shfl_down(vld, off);
  }
  __syncthreads();   // protect shf/shi reuse
  if ((t & 63) == 0) { shf[wv] = contrib; shi[wv] = vld; }
  __syncthreads();
  if (t == 0) {
    float hs = 0.0f; int vc = 0;
    for (int w = 0; w < 6; ++w) { hs += shf[w]; vc += shi[w]; }
    float semi = s_tsum / fmaxf((float)s_tcnt, 1.0f);
    float hard = (vc > 0) ? (hs / (float)vc) : 0.0f;
    out[0] = (s_tcnt > 0) ? semi : hard;
  }
}

extern "C" void kernel_launch(void* const* d_in, const int* in_sizes, int n_in,
                              void* d_out, int out_size, void* d_ws, size_t ws_size,
                              hipStream_t stream) {
  (void)in_sizes; (void)n_in; (void)out_size; (void)ws_size;
  const float* e      = (const float*)d_in[0];
  const int*   labels = (const int*)d_in[1];
  float*       out    = (float*)d_out;

  float* ws       = (float*)d_ws;
  float* semi_sum = ws;              // 384 f32
  float* hp_arr   = ws + N;          // 384 f32
  float* mn_arr   = ws + 2 * N;      // 384 f32
  float* rm_arr   = ws + 3 * N;      // 384 f32
  int*   semi_cnt = (int*)(ws + 4 * N);
  int*   pc_arr   = (int*)(ws + 5 * N);

  k_rows<<<N, TPB, 0, stream>>>(e, labels, semi_sum, semi_cnt,
                                hp_arr, mn_arr, rm_arr, pc_arr);
  k_final<<<1, N, 0, stream>>>(semi_sum, semi_cnt, hp_arr, mn_arr, rm_arr,
                               pc_arr, out);
}

// Round 2
// 73.504 us; speedup vs baseline: 1.1399x; 1.1399x over previous
//
#include <hip/hip_runtime.h>
#include <math.h>

#define N 384
#define D 256
#define D4 (D/4)
#define A 3
#define GRID (N/A)      // 128 blocks
#define TPB N           // 384 threads = 6 waves; j == threadIdx.x
#define NW (TPB/64)     // 6 waves
#define MARGIN_F 0.3f

// K1: one block per A=3 anchors. Each thread owns column j == t.
// Distances via ||ei||^2 + ||ej||^2 - 2*ei.ej (the reference's own form);
// e is streamed from L2 once per block (3x less traffic than 1 anchor/block).
__global__ __launch_bounds__(TPB) void k_rows(const float* __restrict__ e,
                                              const int* __restrict__ labels,
                                              float* __restrict__ semi_sum,
                                              int* __restrict__ semi_cnt,
                                              float* __restrict__ hp_arr,
                                              float* __restrict__ mn_arr,
                                              float* __restrict__ rm_arr,
                                              int* __restrict__ pc_arr) {
  __shared__ float4 ei[A][D4];      // anchor embeddings (broadcast reads)
  __shared__ float  nrm[N];         // ||e_j||^2, written by thread j
  __shared__ float  row[A][N];      // d[anchor][j]
  __shared__ float  negd[A][N];     // d if negative else sentinel
  __shared__ int    lab[N];
  __shared__ int    poslist[A][N];
  __shared__ int    npos[A];
  __shared__ float  wredf[A][4][NW];   // 0:sum 1:hp 2:mn 3:rm
  __shared__ int    wredi[A][2][NW];   // 0:cnt 1:pc

  const int b = blockIdx.x;
  const int t = threadIdx.x;           // == column j
  const int i0 = b * A;

  lab[t] = labels[t];
  if (t < A * D4) {
    int a = t / D4, c = t % D4;
    ei[a][c] = ((const float4*)e)[(size_t)(i0 + a) * D4 + c];
  }
  if (t < A) npos[t] = 0;
  __syncthreads();

  // main loop: this thread's row dot each anchor + its own squared norm
  const float4* ej = (const float4*)(e + (size_t)t * D);
  float4 dv0 = {0,0,0,0}, dv1 = {0,0,0,0}, dv2 = {0,0,0,0}, nv = {0,0,0,0};
#pragma unroll 8
  for (int c = 0; c < D4; ++c) {
    float4 v = ej[c];
    nv.x += v.x*v.x; nv.y += v.y*v.y; nv.z += v.z*v.z; nv.w += v.w*v.w;
    float4 u0 = ei[0][c];
    dv0.x += u0.x*v.x; dv0.y += u0.y*v.y; dv0.z += u0.z*v.z; dv0.w += u0.w*v.w;
    float4 u1 = ei[1][c];
    dv1.x += u1.x*v.x; dv1.y += u1.y*v.y; dv1.z += u1.z*v.z; dv1.w += u1.w*v.w;
    float4 u2 = ei[2][c];
    dv2.x += u2.x*v.x; dv2.y += u2.y*v.y; dv2.z += u2.z*v.z; dv2.w += u2.w*v.w;
  }
  const float nj = (nv.x + nv.y) + (nv.z + nv.w);
  float dots[A];
  dots[0] = (dv0.x + dv0.y) + (dv0.z + dv0.w);
  dots[1] = (dv1.x + dv1.y) + (dv1.z + dv1.w);
  dots[2] = (dv2.x + dv2.y) + (dv2.z + dv2.w);
  nrm[t] = nj;
  __syncthreads();

  const int lj = lab[t];
  float hpv[A], mnv[A], rmv[A];
  int   pcv[A];
#pragma unroll
  for (int a = 0; a < A; ++a) {
    const float ni = nrm[i0 + a];
    float d2 = fmaxf(ni + nj - 2.0f * dots[a], 0.0f);
    float dvv = (d2 > 0.0f) ? sqrtf(d2) : 0.0f;   // ref zmask semantics
    const bool eq    = (lj == lab[i0 + a]);
    const bool ispos = eq && (t != i0 + a);
    row[a][t]  = dvv;
    negd[a][t] = eq ? 1e30f : dvv;   // sentinel never passes validity test
    rmv[a] = dvv;
    mnv[a] = eq ? 1e30f : dvv;
    hpv[a] = ispos ? dvv : 0.0f;     // matches (apf*d).max: 0 if no positives
    pcv[a] = ispos ? 1 : 0;
    if (ispos) { int idx = atomicAdd(&npos[a], 1); poslist[a][idx] = t; }
  }
  __syncthreads();

  const int w = t >> 6;
#pragma unroll
  for (int a = 0; a < A; ++a) {
    // semi-hard: this thread is negative-candidate k==t for every positive j
    const float an = negd[a][t];
    float s = 0.0f;
    int   c = 0;
    const int np = npos[a];
    for (int p = 0; p < np; ++p) {
      const float ap = row[a][poslist[a][p]];   // LDS broadcast
      const float loss = ap - an + MARGIN_F;
      if (an > ap && loss > 0.0f) { s += loss; c++; }
    }
    float hp = hpv[a], mn = mnv[a], rm = rmv[a];
    int   pc = pcv[a];
    for (int off = 32; off; off >>= 1) {
      s  += __shfl_down(s, off);
      c  += __shfl_down(c, off);
      hp  = fmaxf(hp, __shfl_down(hp, off));
      mn  = fminf(mn, __shfl_down(mn, off));
      rm  = fmaxf(rm, __shfl_down(rm, off));
      pc += __shfl_down(pc, off);
    }
    if ((t & 63) == 0) {
      wredf[a][0][w] = s;  wredf[a][1][w] = hp;
      wredf[a][2][w] = mn; wredf[a][3][w] = rm;
      wredi[a][0][w] = c;  wredi[a][1][w] = pc;
    }
  }
  __syncthreads();
  if (t < A) {
    float S = 0.0f, HP = 0.0f, MN = 1e30f, RM = 0.0f;
    int   C = 0, PC = 0;
    for (int ww = 0; ww < NW; ++ww) {
      S += wredf[t][0][ww];
      HP = fmaxf(HP, wredf[t][1][ww]);
      MN = fminf(MN, wredf[t][2][ww]);
      RM = fmaxf(RM, wredf[t][3][ww]);
      C += wredi[t][0][ww];
      PC += wredi[t][1][ww];
    }
    const int i = i0 + t;
    semi_sum[i] = S; semi_cnt[i] = C;
    hp_arr[i] = HP;  mn_arr[i] = MN;
    rm_arr[i] = RM;  pc_arr[i] = PC;
  }
}

// K2: single block of 384 threads (one per row) -> final scalar
__global__ __launch_bounds__(N) void k_final(const float* __restrict__ semi_sum,
                                             const int* __restrict__ semi_cnt,
                                             const float* __restrict__ hp_arr,
                                             const float* __restrict__ mn_arr,
                                             const float* __restrict__ rm_arr,
                                             const int* __restrict__ pc_arr,
                                             float* __restrict__ out) {
  const int t = threadIdx.x;        // 0..383, 6 waves
  __shared__ float shf[12];
  __shared__ int   shi[6];
  __shared__ float s_maxd, s_tsum;
  __shared__ int   s_tcnt;

  float s  = semi_sum[t];
  float rm = rm_arr[t];
  int   c  = semi_cnt[t];
  for (int off = 32; off; off >>= 1) {
    s += __shfl_down(s, off);
    rm = fmaxf(rm, __shfl_down(rm, off));
    c += __shfl_down(c, off);
  }
  const int wv = t >> 6;
  if ((t & 63) == 0) { shf[wv] = s; shf[6 + wv] = rm; shi[wv] = c; }
  __syncthreads();
  if (t == 0) {
    float ts = 0.0f, md = 0.0f; int tc = 0;
    for (int w = 0; w < 6; ++w) { ts += shf[w]; md = fmaxf(md, shf[6 + w]); tc += shi[w]; }
    s_tsum = ts; s_tcnt = tc; s_maxd = md;
  }
  __syncthreads();
  const float maxd = s_maxd;

  // hard loss per row: hardest_neg = min(min_neg, max_d)
  float hp  = hp_arr[t];
  float mnv = mn_arr[t];
  int   pcv = pc_arr[t];
  float hn  = fminf(mnv, maxd);
  float tl  = fmaxf(hp - hn + MARGIN_F, 0.0f);
  int   vld = (pcv > 0) ? 1 : 0;
  float contrib = vld ? tl : 0.0f;
  for (int off = 32; off; off >>= 1) {
    contrib += __shfl_down(contrib, off);
    vld += __shfl_down(vld, off);
  }
  __syncthreads();   // protect shf/shi reuse
  if ((t & 63) == 0) { shf[wv] = contrib; shi[wv] = vld; }
  __syncthreads();
  if (t == 0) {
    float hs = 0.0f; int vc = 0;
    for (int w = 0; w < 6; ++w) { hs += shf[w]; vc += shi[w]; }
    float semi = s_tsum / fmaxf((float)s_tcnt, 1.0f);
    float hard = (vc > 0) ? (hs / (float)vc) : 0.0f;
    out[0] = (s_tcnt > 0) ? semi : hard;
  }
}

extern "C" void kernel_launch(void* const* d_in, const int* in_sizes, int n_in,
                              void* d_out, int out_size, void* d_ws, size_t ws_size,
                              hipStream_t stream) {
  (void)in_sizes; (void)n_in; (void)out_size; (void)ws_size;
  const float* e      = (const float*)d_in[0];
  const int*   labels = (const int*)d_in[1];
  float*       out    = (float*)d_out;

  float* ws       = (float*)d_ws;
  float* semi_sum = ws;              // 384 f32
  float* hp_arr   = ws + N;          // 384 f32
  float* mn_arr   = ws + 2 * N;      // 384 f32
  float* rm_arr   = ws + 3 * N;      // 384 f32
  int*   semi_cnt = (int*)(ws + 4 * N);
  int*   pc_arr   = (int*)(ws + 5 * N);

  k_rows<<<GRID, TPB, 0, stream>>>(e, labels, semi_sum, semi_cnt,
                                   hp_arr, mn_arr, rm_arr, pc_arr);
  k_final<<<1, N, 0, stream>>>(semi_sum, semi_cnt, hp_arr, mn_arr, rm_arr,
                               pc_arr, out);
}